// Round 1
// baseline (219.851 us; speedup 1.0000x reference)
//
#include <hip/hip_runtime.h>
#include <hip/hip_bf16.h>

// CompanyOperationEvaluation: fused-rec-branch MLP+cross-compress pipeline.
// Strategy: bf16 MFMA (16x16x32) for all GEMMs, fp32 accumulate.
// ws layout (~59.3 MB as ushort/bf16): feat_bf, e_buf, h_buf, cf_a, cf_b,
// high(B x 256 = [cf|e]), x0, x1, transposed bf16 weights.

typedef __bf16 bf16x8 __attribute__((ext_vector_type(8)));
typedef float floatx4 __attribute__((ext_vector_type(4)));

__device__ __forceinline__ unsigned short f2bf(float x) {
  unsigned int u = __builtin_bit_cast(unsigned int, x);
  u = (u + 0x7FFFu + ((u >> 16) & 1u)) >> 16;
  return (unsigned short)u;
}
__device__ __forceinline__ float bf2f(unsigned short h) {
  return __builtin_bit_cast(float, (unsigned int)h << 16);
}

// ---------------------------------------------------------------------------
// prep: features fp32->bf16 | gather ent/head rows -> bf16 | transpose+convert
// all weight matrices to N x K bf16 (so MFMA B-fragments read contiguous K).
// grid = 2048 (features) + 2048 (gather) + 1224 (transposes) = 5320 blocks.
// ---------------------------------------------------------------------------
__global__ __launch_bounds__(256) void prep_kernel(
    const float* __restrict__ features, const int* __restrict__ ent_idx,
    const float* __restrict__ head_tab, const float* __restrict__ ent_tab,
    const float* __restrict__ Wf, const float* __restrict__ Wu,
    const float* __restrict__ W0, const float* __restrict__ W1,
    const float* __restrict__ W2,
    unsigned short* __restrict__ feat_bf, unsigned short* __restrict__ e_buf,
    unsigned short* __restrict__ h_buf,
    unsigned short* __restrict__ wfT, unsigned short* __restrict__ wuT,
    unsigned short* __restrict__ w0T, unsigned short* __restrict__ w1T,
    unsigned short* __restrict__ w2T) {
  const int bid = blockIdx.x, tid = threadIdx.x;
  if (bid < 2048) {
    // features: 16384*256 fp32 -> bf16, 8 elems/thread, coalesced.
    size_t base = (size_t)bid * 2048 + (size_t)tid * 8;
    float4 f0 = *(const float4*)(features + base);
    float4 f1 = *(const float4*)(features + base + 4);
    uint4 v;
    v.x = (unsigned)f2bf(f0.x) | ((unsigned)f2bf(f0.y) << 16);
    v.y = (unsigned)f2bf(f0.z) | ((unsigned)f2bf(f0.w) << 16);
    v.z = (unsigned)f2bf(f1.x) | ((unsigned)f2bf(f1.y) << 16);
    v.w = (unsigned)f2bf(f1.z) | ((unsigned)f2bf(f1.w) << 16);
    *(uint4*)(feat_bf + base) = v;
  } else if (bid < 4096) {
    // gather: 8 rows/block, 32 lanes/row, float4 per lane (128 elems/row).
    int r = (bid - 2048) * 8 + (tid >> 5);
    int c = (tid & 31) * 4;
    int idx = ent_idx[r];
    float4 ev = *(const float4*)(ent_tab + (size_t)idx * 128 + c);
    float4 hv = *(const float4*)(head_tab + (size_t)idx * 128 + c);
    uint2 eo, ho;
    eo.x = (unsigned)f2bf(ev.x) | ((unsigned)f2bf(ev.y) << 16);
    eo.y = (unsigned)f2bf(ev.z) | ((unsigned)f2bf(ev.w) << 16);
    ho.x = (unsigned)f2bf(hv.x) | ((unsigned)f2bf(hv.y) << 16);
    ho.y = (unsigned)f2bf(hv.z) | ((unsigned)f2bf(hv.w) << 16);
    *(uint2*)(e_buf + (size_t)r * 128 + c) = eo;
    *(uint2*)(h_buf + (size_t)r * 128 + c) = ho;
  } else {
    // weight transposes: src row-major (K x N), read coalesced, write N x K.
    int g = (bid - 4096) * 256 + tid;  // 0 .. 313343
    if (g < 32768) {                       // Wf 256x128
      int k = g >> 7, n = g & 127;  wfT[n * 256 + k] = f2bf(Wf[g]);
    } else if (g < 49152) {                // Wu 128x128
      int l = g - 32768; int k = l >> 7, n = l & 127;
      wuT[n * 128 + k] = f2bf(Wu[l]);
    } else if (g < 180224) {               // W0 256x512
      int l = g - 49152; int k = l >> 9, n = l & 511;
      w0T[n * 256 + k] = f2bf(W0[l]);
    } else if (g < 311296) {               // W1 512x256
      int l = g - 180224; int k = l >> 8, n = l & 255;
      w1T[n * 512 + k] = f2bf(W1[l]);
    } else {                               // W2 256x8
      int l = g - 311296; int k = l >> 3, n = l & 7;
      w2T[n * 256 + k] = f2bf(W2[l]);
    }
  }
}

// ---------------------------------------------------------------------------
// GEMM: C(M x N) = relu(A(M x K) @ B + bias), A bf16 row-major, B given as
// BT (N x K) bf16 row-major. Tile 128x64, BK=64, 4 waves in 2x2, each wave
// 64x32 via 4x2 16x16x32 MFMAs. LDS rows padded to 72 bf16 (144B = 9*16B):
// frag ds_read_b128 lands 2-way bank-aliased (free, m136).
// grid: (N/64, M/128), 256 threads.
// ---------------------------------------------------------------------------
__global__ __launch_bounds__(256) void gemm_kernel(
    const unsigned short* __restrict__ A, const unsigned short* __restrict__ BT,
    const float* __restrict__ bias, unsigned short* __restrict__ C,
    int K, int ldc) {
  __shared__ __align__(16) unsigned short a_sh[128 * 72];  // 18 KB
  __shared__ __align__(16) unsigned short b_sh[64 * 72];   // 9 KB
  const int tid = threadIdx.x;
  const int bn = blockIdx.x, bm = blockIdx.y;
  const int lane = tid & 63;
  const int wave = tid >> 6;
  const int wm = wave & 1, wn = wave >> 1;
  const int m16 = lane & 15, quad = lane >> 4;

  floatx4 acc[4][2];
#pragma unroll
  for (int i = 0; i < 4; ++i)
#pragma unroll
    for (int j = 0; j < 2; ++j) acc[i][j] = (floatx4){0.f, 0.f, 0.f, 0.f};

  for (int k0 = 0; k0 < K; k0 += 64) {
    // stage A 128x64 (1024 16B-chunks) + BT 64x64 (512 chunks)
#pragma unroll
    for (int i = 0; i < 4; ++i) {
      int chunk = i * 256 + tid;
      int row = chunk >> 3, seg = chunk & 7;
      *(uint4*)&a_sh[row * 72 + seg * 8] =
          *(const uint4*)(A + (size_t)(bm * 128 + row) * K + k0 + seg * 8);
    }
#pragma unroll
    for (int i = 0; i < 2; ++i) {
      int chunk = i * 256 + tid;
      int row = chunk >> 3, seg = chunk & 7;
      *(uint4*)&b_sh[row * 72 + seg * 8] =
          *(const uint4*)(BT + (size_t)(bn * 64 + row) * K + k0 + seg * 8);
    }
    __syncthreads();
#pragma unroll
    for (int kk = 0; kk < 64; kk += 32) {
      bf16x8 af[4], bfr[2];
#pragma unroll
      for (int mi = 0; mi < 4; ++mi)
        af[mi] = *(const bf16x8*)&a_sh[(wm * 64 + mi * 16 + m16) * 72 + kk + quad * 8];
#pragma unroll
      for (int ni = 0; ni < 2; ++ni)
        bfr[ni] = *(const bf16x8*)&b_sh[(wn * 32 + ni * 16 + m16) * 72 + kk + quad * 8];
#pragma unroll
      for (int mi = 0; mi < 4; ++mi)
#pragma unroll
        for (int ni = 0; ni < 2; ++ni)
          acc[mi][ni] = __builtin_amdgcn_mfma_f32_16x16x32_bf16(
              af[mi], bfr[ni], acc[mi][ni], 0, 0, 0);
    }
    __syncthreads();
  }
  // epilogue: C/D layout col=lane&15, row=quad*4+reg (m89-verified mapping)
#pragma unroll
  for (int mi = 0; mi < 4; ++mi) {
#pragma unroll
    for (int ni = 0; ni < 2; ++ni) {
      int col = bn * 64 + wn * 32 + ni * 16 + m16;
      float bv = bias[col];
#pragma unroll
      for (int r = 0; r < 4; ++r) {
        int row = bm * 128 + wm * 64 + mi * 16 + quad * 4 + r;
        float v = acc[mi][ni][r] + bv;
        v = fmaxf(v, 0.f);
        C[(size_t)row * ldc + col] = f2bf(v);
      }
    }
  }
}

// ---------------------------------------------------------------------------
// cross_compress, both iterations fused. 1 wave/block, 4 rows/wave,
// 16 lanes/row, 8 elems/lane. Dots reduced via shfl_xor within 16-lane group.
// Writes final e into high[:, 128:256]. h result is dead after iter 2.
// ---------------------------------------------------------------------------
__global__ __launch_bounds__(64) void cross_kernel(
    const unsigned short* __restrict__ h_buf, const unsigned short* __restrict__ e_buf,
    const float* __restrict__ w_cf, const float* __restrict__ w_fc,
    const float* __restrict__ w_ef, const float* __restrict__ w_fe,
    const float* __restrict__ b_c, const float* __restrict__ b_e,
    unsigned short* __restrict__ high) {
  const int lane = threadIdx.x;
  const int rl = lane >> 4, seg = lane & 15;
  const int row = blockIdx.x * 4 + rl;
  const int cb = seg * 8;
  float h[8], e[8], wcf[8], wfc[8], wef[8], wfe[8];
  const unsigned short* hp = h_buf + (size_t)row * 128 + cb;
  const unsigned short* ep = e_buf + (size_t)row * 128 + cb;
#pragma unroll
  for (int j = 0; j < 8; ++j) { h[j] = bf2f(hp[j]); e[j] = bf2f(ep[j]); }
#pragma unroll
  for (int j = 0; j < 8; ++j) {
    wcf[j] = w_cf[cb + j]; wfc[j] = w_fc[cb + j];
    wef[j] = w_ef[cb + j]; wfe[j] = w_fe[cb + j];
  }
  const float bc = b_c[0], be = b_e[0];
#pragma unroll
  for (int it = 0; it < 2; ++it) {
    float d0 = 0, d1 = 0, d2 = 0, d3 = 0;
#pragma unroll
    for (int j = 0; j < 8; ++j) {
      d0 += e[j] * wcf[j];  // e . w_cf
      d1 += h[j] * wfc[j];  // f . w_fc
      d2 += e[j] * wef[j];  // e . w_ef
      d3 += h[j] * wfe[j];  // f . w_fe
    }
#pragma unroll
    for (int s = 1; s < 16; s <<= 1) {
      d0 += __shfl_xor(d0, s); d1 += __shfl_xor(d1, s);
      d2 += __shfl_xor(d2, s); d3 += __shfl_xor(d3, s);
    }
    float nh[8], ne[8];
#pragma unroll
    for (int j = 0; j < 8; ++j) {
      nh[j] = h[j] * d0 + e[j] * d1 + bc;  // new_f = f*ew_cf + e*fw_fc + b_c
      ne[j] = h[j] * d2 + e[j] * d3 + be;  // new_e = f*ew_ef + e*fw_fe + b_e
    }
#pragma unroll
    for (int j = 0; j < 8; ++j) { h[j] = nh[j]; e[j] = ne[j]; }
  }
  uint4 v;
  v.x = (unsigned)f2bf(e[0]) | ((unsigned)f2bf(e[1]) << 16);
  v.y = (unsigned)f2bf(e[2]) | ((unsigned)f2bf(e[3]) << 16);
  v.z = (unsigned)f2bf(e[4]) | ((unsigned)f2bf(e[5]) << 16);
  v.w = (unsigned)f2bf(e[6]) | ((unsigned)f2bf(e[7]) << 16);
  *(uint4*)(high + (size_t)row * 256 + 128 + cb) = v;
}

// ---------------------------------------------------------------------------
// final: logits = relu(x1 @ W2 + b2), softmax, write prob + target-as-float.
// 1 wave/row (4 rows/block); lane covers 4 K-elems; 8 dots shfl-reduced.
// ---------------------------------------------------------------------------
__global__ __launch_bounds__(256) void final_kernel(
    const unsigned short* __restrict__ x1, const unsigned short* __restrict__ w2T,
    const float* __restrict__ b2, const int* __restrict__ target,
    float* __restrict__ out) {
  const int lane = threadIdx.x & 63;
  const int row = blockIdx.x * 4 + (threadIdx.x >> 6);
  float x[4];
  {
    const unsigned short* xp = x1 + (size_t)row * 256 + lane * 4;
#pragma unroll
    for (int j = 0; j < 4; ++j) x[j] = bf2f(xp[j]);
  }
  float p[8];
#pragma unroll
  for (int n = 0; n < 8; ++n) {
    const unsigned short* wp = w2T + n * 256 + lane * 4;
    float s = 0.f;
#pragma unroll
    for (int j = 0; j < 4; ++j) s += x[j] * bf2f(wp[j]);
    p[n] = s;
  }
#pragma unroll
  for (int s = 1; s < 64; s <<= 1) {
#pragma unroll
    for (int n = 0; n < 8; ++n) p[n] += __shfl_xor(p[n], s);
  }
  float mx = -1e30f;
#pragma unroll
  for (int n = 0; n < 8; ++n) {
    p[n] = fmaxf(p[n] + b2[n], 0.f);
    mx = fmaxf(mx, p[n]);
  }
  float sum = 0.f;
#pragma unroll
  for (int n = 0; n < 8; ++n) { p[n] = __expf(p[n] - mx); sum += p[n]; }
  const float inv = 1.f / sum;
  if (lane < 8) out[(size_t)row * 8 + lane] = p[lane] * inv;
  if (lane == 8) out[(size_t)(16384 * 8) + row] = (float)target[row];
}

extern "C" void kernel_launch(void* const* d_in, const int* in_sizes, int n_in,
                              void* d_out, int out_size, void* d_ws, size_t ws_size,
                              hipStream_t stream) {
  const float* features = (const float*)d_in[0];
  const int* ent_idx    = (const int*)d_in[1];
  const int* target     = (const int*)d_in[2];
  const float* Wf  = (const float*)d_in[3];
  const float* bf  = (const float*)d_in[4];
  const float* Wu  = (const float*)d_in[5];
  const float* bu  = (const float*)d_in[6];
  const float* w_cf = (const float*)d_in[7];
  const float* w_fc = (const float*)d_in[8];
  const float* w_ef = (const float*)d_in[9];
  const float* w_fe = (const float*)d_in[10];
  const float* b_c  = (const float*)d_in[11];
  const float* b_e  = (const float*)d_in[12];
  const float* head_tab = (const float*)d_in[13];
  const float* ent_tab  = (const float*)d_in[14];
  const float* W0 = (const float*)d_in[15];
  const float* b0 = (const float*)d_in[16];
  const float* W1 = (const float*)d_in[17];
  const float* b1 = (const float*)d_in[18];
  const float* W2 = (const float*)d_in[19];
  const float* b2 = (const float*)d_in[20];
  float* out = (float*)d_out;

  // ws carve-up (ushort units; every size is a multiple of 8 -> 16B aligned).
  // Total ~59.3 MB.
  unsigned short* ws = (unsigned short*)d_ws;
  size_t off = 0;
  auto alloc = [&](size_t n) { unsigned short* p = ws + off; off += n; return p; };
  unsigned short* feat_bf = alloc(16384ull * 256);
  unsigned short* e_buf   = alloc(16384ull * 128);
  unsigned short* h_buf   = alloc(16384ull * 128);
  unsigned short* cf_a    = alloc(16384ull * 128);
  unsigned short* cf_b    = alloc(16384ull * 128);
  unsigned short* high    = alloc(16384ull * 256);
  unsigned short* x0      = alloc(16384ull * 512);
  unsigned short* x1      = alloc(16384ull * 256);
  unsigned short* wfT = alloc(32768);
  unsigned short* wuT = alloc(16384);
  unsigned short* w0T = alloc(131072);
  unsigned short* w1T = alloc(131072);
  unsigned short* w2T = alloc(2048);
  (void)ws_size; (void)in_sizes; (void)n_in; (void)out_size;

  prep_kernel<<<5320, 256, 0, stream>>>(features, ent_idx, head_tab, ent_tab,
      Wf, Wu, W0, W1, W2, feat_bf, e_buf, h_buf, wfT, wuT, w0T, w1T, w2T);
  // cf0 = relu(feat @ Wf + bf)
  gemm_kernel<<<dim3(2, 128), 256, 0, stream>>>(feat_bf, wfT, bf, cf_a, 256, 128);
  // cf1 = relu(cf0 @ Wu + bu)
  gemm_kernel<<<dim3(2, 128), 256, 0, stream>>>(cf_a, wuT, bu, cf_b, 128, 128);
  // cf2 = relu(cf1 @ Wu + bu) -> high[:, 0:128]
  gemm_kernel<<<dim3(2, 128), 256, 0, stream>>>(cf_b, wuT, bu, high, 128, 256);
  // cross_compress x2 -> high[:, 128:256]
  cross_kernel<<<4096, 64, 0, stream>>>(h_buf, e_buf, w_cf, w_fc, w_ef, w_fe,
                                        b_c, b_e, high);
  // x0 = relu(high @ W0 + b0)
  gemm_kernel<<<dim3(8, 128), 256, 0, stream>>>(high, w0T, b0, x0, 256, 512);
  // x1 = relu(x0 @ W1 + b1)
  gemm_kernel<<<dim3(4, 128), 256, 0, stream>>>(x0, w1T, b1, x1, 512, 256);
  // logits/softmax/output
  final_kernel<<<4096, 256, 0, stream>>>(x1, w2T, b2, target, out);
}